// Round 9
// baseline (229.853 us; speedup 1.0000x reference)
//
#include <hip/hip_runtime.h>
#include <hip/hip_bf16.h>
#include <stdint.h>

#define S_LEN 4096

typedef short s16x8  __attribute__((ext_vector_type(8)));
typedef float f32x4  __attribute__((ext_vector_type(4)));
typedef float f32x16 __attribute__((ext_vector_type(16)));

// log2(e)/8 : folded into Q at QKV epilogue; attn does exp2(score) directly
#define CEXP 0.18033688011112042f

__device__ __forceinline__ unsigned short f2bf(float f) {
    union { float f; unsigned u; } v; v.f = f;
    unsigned r = v.u + 0x7fffu + ((v.u >> 16) & 1u);
    return (unsigned short)(r >> 16);
}

__device__ __forceinline__ ushort2 pkbf(float a, float b) {
    float2 f; f.x = a; f.y = b;
    __hip_bfloat162 h = __float22bfloat162_rn(f);
    union { __hip_bfloat162 h; ushort2 u; } cv; cv.h = h;
    return cv.u;
}

__device__ __forceinline__ ushort4 pkbf4(float x, float y, float z, float w) {
    ushort2 lo = pkbf(x, y), hi = pkbf(z, w);
    ushort4 r; r.x = lo.x; r.y = lo.y; r.z = hi.x; r.w = hi.y;
    return r;
}

__device__ __forceinline__ unsigned pku(float a, float b) {
    union { ushort2 s; unsigned u; } c; c.s = pkbf(a, b); return c.u;
}

typedef const __attribute__((address_space(1))) void* gas_t;
typedef __attribute__((address_space(3))) void* sas_t;

__device__ __forceinline__ void async16(const void* g, void* s) {
    __builtin_amdgcn_global_load_lds((gas_t)g, (sas_t)s, 16, 0, 0);
}

// ---------------------------------------------------------------------------
// fp32 -> bf16 convert for X (4194304) and W (3145728). 8 elems/thread.
// ---------------------------------------------------------------------------
__global__ __launch_bounds__(256) void cvt_bf16(
    const float* __restrict__ X, const float* __restrict__ W,
    unsigned short* __restrict__ Xb, unsigned short* __restrict__ Wb)
{
    const long NX = 4194304;
    long i = (long)(blockIdx.x * 256 + threadIdx.x) * 8;
    const float* src; unsigned short* dst; long off;
    if (i < NX) { src = X; dst = Xb; off = i; }
    else        { src = W; dst = Wb; off = i - NX; }
    float4 a = *(const float4*)(src + off);
    float4 b = *(const float4*)(src + off + 4);
    union { s16x8 v; ushort4 q[2]; } o;
    o.q[0] = pkbf4(a.x, a.y, a.z, a.w);
    o.q[1] = pkbf4(b.x, b.y, b.z, b.w);
    *(s16x8*)(dst + off) = o.v;
}

// ---------------------------------------------------------------------------
// Kernel A (primary): qkv = Xb @ Wb^T + b, bf16 in. (R7 version, unchanged)
// BK=32 dbuf (2x16KB staging, 34816B LDS block) -> 4 blocks/CU, all 768
// blocks resident, 1 barrier/kt. Vectorized Q/K epilogue.
// ---------------------------------------------------------------------------
__global__ __launch_bounds__(256) void qkv_gemm_bf16(
    const unsigned short* __restrict__ Xb, const unsigned short* __restrict__ Wb,
    const float* __restrict__ bias, const float* __restrict__ trace,
    unsigned short* __restrict__ Qb, unsigned short* __restrict__ Kb,
    unsigned short* __restrict__ Vt)
{
    __shared__ __align__(16) unsigned short sm[17408];   // 34816 B

    const int t = threadIdx.x;
    const int l = t & 63;
    const int w = t >> 6;
    const int bm = blockIdx.y, bn = blockIdx.x;
    const int rowBase = (w >> 1) * 64;
    const int colBase = (w & 1) * 64;

    f32x4 acc[4][4];
#pragma unroll
    for (int i = 0; i < 4; i++)
#pragma unroll
        for (int j = 0; j < 4; j++) acc[i][j] = (f32x4)0.f;

    const int p0 = w * 128 + l;
    const int p1 = p0 + 64;
    const int ar0 = p0 >> 2, ac0 = (p0 & 3) * 8;
    const int ar1 = p1 >> 2, ac1 = (p1 & 3) * 8;

    async16(Xb + (bm * 128 + ar0) * 1024 + ac0, sm + p0 * 8);
    async16(Xb + (bm * 128 + ar1) * 1024 + ac1, sm + p1 * 8);
    async16(Wb + (bn * 128 + ar0) * 1024 + ac0, sm + 4096 + p0 * 8);
    async16(Wb + (bn * 128 + ar1) * 1024 + ac1, sm + 4096 + p1 * 8);

    for (int kt = 0; kt < 32; ++kt) {
        __syncthreads();
        const unsigned short* As = sm + (kt & 1) * 8192;
        const unsigned short* Bs = As + 4096;

        if (kt < 31) {
            const int k0 = (kt + 1) * 32;
            unsigned short* An = sm + ((kt + 1) & 1) * 8192;
            async16(Xb + (bm * 128 + ar0) * 1024 + k0 + ac0, An + p0 * 8);
            async16(Xb + (bm * 128 + ar1) * 1024 + k0 + ac1, An + p1 * 8);
            async16(Wb + (bn * 128 + ar0) * 1024 + k0 + ac0, An + 4096 + p0 * 8);
            async16(Wb + (bn * 128 + ar1) * 1024 + k0 + ac1, An + 4096 + p1 * 8);
        }

        s16x8 af[4], bf[4];
#pragma unroll
        for (int i = 0; i < 4; i++) {
            af[i] = *(const s16x8*)(As + (rowBase + i * 16 + (l & 15)) * 32 + (l >> 4) * 8);
            bf[i] = *(const s16x8*)(Bs + (colBase + i * 16 + (l & 15)) * 32 + (l >> 4) * 8);
        }
#pragma unroll
        for (int i = 0; i < 4; i++)
#pragma unroll
            for (int j = 0; j < 4; j++)
                acc[i][j] = __builtin_amdgcn_mfma_f32_16x16x32_bf16(af[i], bf[j], acc[i][j], 0, 0, 0);
    }

    __syncthreads();

    if (bn < 16) {
        unsigned short* Ls = sm;                  // [128 s][136 c]
        const int region = bn >> 3;
        unsigned short* dst = region ? Kb : Qb;
        const float scl = region ? 1.0f : CEXP;
#pragma unroll
        for (int j = 0; j < 4; j++) {
            int cl = colBase + j * 16 + (l & 15);
            float bv = bias[bn * 128 + cl];
#pragma unroll
            for (int i = 0; i < 4; i++) {
                int s0 = rowBase + i * 16 + ((l >> 4) << 2);
#pragma unroll
                for (int r = 0; r < 4; r++)
                    Ls[(s0 + r) * 136 + cl] = f2bf((acc[i][j][r] + bv) * scl);
            }
        }
        __syncthreads();
#pragma unroll
        for (int p = 0; p < 8; ++p) {
            int tk = p * 256 + t;
            int s  = tk >> 4;
            int ch = tk & 15;
            int gc = bn * 128 + ch * 8;
            int h  = (gc >> 6) & 15, d = gc & 63;
            s16x8 v = *(const s16x8*)(Ls + s * 136 + ch * 8);
            *(s16x8*)(dst + (h * S_LEN + bm * 128 + s) * 64 + d) = v;
        }
    } else {
        unsigned short* Lt = sm;              // 128 x 136
#pragma unroll
        for (int j = 0; j < 4; j++) {
            int cl = colBase + j * 16 + (l & 15);
            int o  = bn * 128 + cl - 2048;
            float bv = bias[bn * 128 + cl];
            float tr = trace[(o >> 6) * 4096 + (o & 63) * 65];
#pragma unroll
            for (int i = 0; i < 4; i++) {
                int s0 = rowBase + i * 16 + ((l >> 4) << 2);
                *(ushort4*)(Lt + cl * 136 + s0) =
                    pkbf4((acc[i][j][0] + bv) * tr, (acc[i][j][1] + bv) * tr,
                          (acc[i][j][2] + bv) * tr, (acc[i][j][3] + bv) * tr);
            }
        }
        __syncthreads();
#pragma unroll
        for (int p = 0; p < 8; ++p) {
            int dl  = (t >> 4) + p * 16;
            int sch = (t & 15) * 8;
            int o = bn * 128 + dl - 2048;
            int h = o >> 6, d = o & 63;
            s16x8 v = *(const s16x8*)(Lt + dl * 136 + sch);
            *(s16x8*)(Vt + (h * 64 + d) * S_LEN + bm * 128 + sch) = v;
        }
    }
}

// ---------------------------------------------------------------------------
// Kernel A (fallback, small ws): fp32-staged GEMM, same outputs (unchanged)
// ---------------------------------------------------------------------------
__global__ __launch_bounds__(256) void qkv_gemm_f32(
    const float* __restrict__ X, const float* __restrict__ W,
    const float* __restrict__ bias, const float* __restrict__ trace,
    unsigned short* __restrict__ Qb, unsigned short* __restrict__ Kb,
    unsigned short* __restrict__ Vt)
{
    __shared__ __align__(16) unsigned short sm[17408];
    unsigned short* As = sm;
    unsigned short* Bs = sm + 5120;

    const int t = threadIdx.x;
    const int l = t & 63;
    const int w = t >> 6;
    const int bm = blockIdx.y, bn = blockIdx.x;
    const int rowBase = (w >> 1) * 64;
    const int colBase = (w & 1) * 64;

    f32x4 acc[4][4];
#pragma unroll
    for (int i = 0; i < 4; i++)
#pragma unroll
        for (int j = 0; j < 4; j++) acc[i][j] = (f32x4)0.f;

    const int sr = t >> 3;
    const int sc = (t & 7) * 4;

    for (int kt = 0; kt < 32; ++kt) {
        const int k0 = kt * 32;
#pragma unroll
        for (int p = 0; p < 4; ++p) {
            int r = sr + p * 32;
            float4 xa = *(const float4*)(X + (bm * 128 + r) * 1024 + k0 + sc);
            float4 wb = *(const float4*)(W + (bn * 128 + r) * 1024 + k0 + sc);
            *(ushort4*)(As + r * 40 + sc) = pkbf4(xa.x, xa.y, xa.z, xa.w);
            *(ushort4*)(Bs + r * 40 + sc) = pkbf4(wb.x, wb.y, wb.z, wb.w);
        }
        __syncthreads();

        s16x8 af[4], bf[4];
#pragma unroll
        for (int i = 0; i < 4; i++) {
            af[i] = *(const s16x8*)(As + (rowBase + i * 16 + (l & 15)) * 40 + (l >> 4) * 8);
            bf[i] = *(const s16x8*)(Bs + (colBase + i * 16 + (l & 15)) * 40 + (l >> 4) * 8);
        }
#pragma unroll
        for (int i = 0; i < 4; i++)
#pragma unroll
            for (int j = 0; j < 4; j++)
                acc[i][j] = __builtin_amdgcn_mfma_f32_16x16x32_bf16(af[i], bf[j], acc[i][j], 0, 0, 0);
        __syncthreads();
    }

    if (bn < 16) {
#pragma unroll
        for (int j = 0; j < 4; j++) {
            int col = bn * 128 + colBase + j * 16 + (l & 15);
            float bv = bias[col];
            int region = col >> 10;
            int within = col & 1023;
            int h = within >> 6, d = within & 63;
            unsigned short* dst = (region == 0) ? Qb : Kb;
            float scl = (region == 0) ? CEXP : 1.0f;
#pragma unroll
            for (int i = 0; i < 4; i++) {
                int s0 = bm * 128 + rowBase + i * 16 + ((l >> 4) << 2);
#pragma unroll
                for (int r = 0; r < 4; r++)
                    dst[(h * S_LEN + s0 + r) * 64 + d] = f2bf((acc[i][j][r] + bv) * scl);
            }
        }
    } else {
        __syncthreads();
        unsigned short* Lt = sm;
#pragma unroll
        for (int j = 0; j < 4; j++) {
            int cl = colBase + j * 16 + (l & 15);
            int o  = bn * 128 + cl - 2048;
            float bv = bias[bn * 128 + cl];
            float tr = trace[(o >> 6) * 4096 + (o & 63) * 65];
#pragma unroll
            for (int i = 0; i < 4; i++) {
                int s0 = rowBase + i * 16 + ((l >> 4) << 2);
                *(ushort4*)(Lt + cl * 136 + s0) =
                    pkbf4((acc[i][j][0] + bv) * tr, (acc[i][j][1] + bv) * tr,
                          (acc[i][j][2] + bv) * tr, (acc[i][j][3] + bv) * tr);
            }
        }
        __syncthreads();
#pragma unroll
        for (int p = 0; p < 8; ++p) {
            int dl  = (t >> 4) + p * 16;
            int sch = (t & 15) * 8;
            int o = bn * 128 + dl - 2048;
            int h = o >> 6, d = o & 63;
            s16x8 v = *(const s16x8*)(Lt + dl * 136 + sch);
            *(s16x8*)(Vt + (h * 64 + d) * S_LEN + bm * 128 + sch) = v;
        }
    }
}

// ---------------------------------------------------------------------------
// Kernel B: flash attention. R9:
//  - K/V staging REVERTED to R7's linear [64][64]+XOR layout (R8's padded
//    layout killed conflicts 8.52M->131K but LOST 2 µs: conflicts are fully
//    latency-hidden; the pad traffic + extra DMA instrs were pure cost).
//  - NEW: l-sum moved off the VALU onto the matrix pipe. The PV B-fragment
//    pb already holds P^T; one extra mfma(ones, pb, lAcc) per PVBLK gives
//    lAcc[r][q] = sum_k P[k][q] (all 16 regs + both half-lanes identical ->
//    l_tot = lAcc[0], shfl_xor dies). Removes 32 v_add_f32/kt (~27% of the
//    removable VALU work; VALUBusy was 55%, the binding pipe). l now sums
//    the same bf16-rounded P that PV uses -> exactly-normalized weights.
// ---------------------------------------------------------------------------
__global__ __launch_bounds__(512, 4) void attn(
    const unsigned short* __restrict__ Qb, const unsigned short* __restrict__ Kb,
    const unsigned short* __restrict__ Vt, float* __restrict__ out)
{
    __shared__ __align__(16) unsigned short sm[34816];   // 69632 B
    __shared__ float lArr[256];

    const int t = threadIdx.x;
    const int l = t & 63;
    const int w = t >> 6;            // 0..7
    const int g = w >> 2;            // kv half
    const int wg = w & 3;            // wave within group
    const int wq = w & 3;            // q sub-tile
    // XCD swizzle: xcd = bid%8 owns heads {2*xcd, 2*xcd+1}
    const int bid = blockIdx.x;
    const int xcd = bid & 7;
    const int j   = bid >> 3;        // 0..63
    const int h   = xcd * 2 + (j & 1);
    const int qblk = j >> 1;         // 0..31
    const int qbase = qblk * 128 + wq * 32;
    const int l31 = l & 31;
    const int lh  = l >> 5;
    const int swz = l31 & 7;         // read-side XOR (row&7)

    s16x8 qf[4];
#pragma unroll
    for (int ks = 0; ks < 4; ks++)
        qf[ks] = *(const s16x8*)(Qb + (h * S_LEN + qbase + l31) * 64 + ks * 16 + lh * 8);

    // bf16 1.0 A-fragment for the l-sum MFMA
    s16x8 ones;
#pragma unroll
    for (int i = 0; i < 8; i++) ones[i] = (short)0x3F80;

    f32x16 O0 = (f32x16)0.f, O1 = (f32x16)0.f;
    f32x16 lAcc = (f32x16)0.f;

    // --- DMA staging addresses (R7 layout) -------------------------------
    const int p0 = (wg * 2 + 0) * 64 + l;
    const int p1 = (wg * 2 + 1) * 64 + l;
    const int r0_ = p0 >> 3, c0_ = (p0 & 7) ^ (r0_ & 7);
    const int r1_ = p1 >> 3, c1_ = (p1 & 7) ^ (r1_ & 7);
    const unsigned short* gk0 = Kb + (h * S_LEN + g * 2048 + r0_) * 64 + c0_ * 8;
    const unsigned short* gk1 = Kb + (h * S_LEN + g * 2048 + r1_) * 64 + c1_ * 8;
    const unsigned short* gv0 = Vt + (h * 64 + r0_) * S_LEN + g * 2048 + c0_ * 8;
    const unsigned short* gv1 = Vt + (h * 64 + r1_) * S_LEN + g * 2048 + c1_ * 8;

    // prologue: stage tile 0 into buf 0
    {
        unsigned short* kb_ = sm + g * 8192 + wg * 1024;
        async16(gk0, kb_);
        async16(gk1, kb_ + 512);
        async16(gv0, kb_ + 4096);
        async16(gv1, kb_ + 4096 + 512);
    }

    for (int kt = 0; kt < 32; ++kt) {
        __syncthreads();   // implicit vmcnt(0): buf[kt&1] DMA done everywhere;
                           // all waves finished reading buf[kt&1 ^ 1]
        const unsigned short* sb  = sm + ((kt & 1) * 2 + g) * 8192;
        const unsigned short* vbs = sb + 4096;

        // issue next tile's DMA into the other buffer (zero registers)
        if (kt < 31) {
            gk0 += 4096; gk1 += 4096; gv0 += 64; gv1 += 64;
            unsigned short* kb_ = sm + (((kt + 1) & 1) * 2 + g) * 8192 + wg * 1024;
            async16(gk0, kb_);
            async16(gk1, kb_ + 512);
            async16(gv0, kb_ + 4096);
            async16(gv1, kb_ + 4096 + 512);
        }

        // S^T[kv][q] = K x Q^T  (scores pre-scaled via Q); swizzled reads
        f32x16 S0 = (f32x16)0.f, S1 = (f32x16)0.f;
        __builtin_amdgcn_s_setprio(1);
#pragma unroll
        for (int ks = 0; ks < 4; ks++) {
            const int off = ((ks * 2 + lh) ^ swz) * 8;
            s16x8 a0 = *(const s16x8*)(sb + l31 * 64 + off);
            s16x8 a1 = *(const s16x8*)(sb + (32 + l31) * 64 + off);
            S0 = __builtin_amdgcn_mfma_f32_32x32x16_bf16(a0, qf[ks], S0, 0, 0, 0);
            S1 = __builtin_amdgcn_mfma_f32_32x32x16_bf16(a1, qf[ks], S1, 0, 0, 0);
        }
        __builtin_amdgcn_s_setprio(0);

        // exp2 only — no VALU accumulation (l-sum rides the matrix pipe now)
#pragma unroll
        for (int i = 0; i < 16; ++i) S0[i] = __builtin_amdgcn_exp2f(S0[i]);
#pragma unroll
        for (int i = 0; i < 16; ++i) S1[i] = __builtin_amdgcn_exp2f(S1[i]);

        // T12: O^T[d][q] += V^T x P^T, P built in-register (R1-verified map);
        // + l-sum MFMA: lAcc = ones x P^T (accumulates sum_k P[k][q] per col q)
        __builtin_amdgcn_s_setprio(1);
#define PVBLK(SX, BO, KS) do {                                               \
        unsigned pa0 = pku(SX[(BO)+0], SX[(BO)+1]);                          \
        unsigned pc0 = pku(SX[(BO)+4], SX[(BO)+5]);                          \
        unsigned pa1 = pku(SX[(BO)+2], SX[(BO)+3]);                          \
        unsigned pc1 = pku(SX[(BO)+6], SX[(BO)+7]);                          \
        auto r0 = __builtin_amdgcn_permlane32_swap(pa0, pc0, false, false);  \
        auto r1 = __builtin_amdgcn_permlane32_swap(pa1, pc1, false, false);  \
        union { s16x8 v; unsigned u[4]; } pb_;                               \
        pb_.u[0] = r0[0]; pb_.u[1] = r1[0]; pb_.u[2] = r0[1]; pb_.u[3] = r1[1]; \
        const int offv = (((KS) * 2 + lh) ^ swz) * 8;                        \
        s16x8 av0 = *(const s16x8*)(vbs + l31 * 64 + offv);                  \
        s16x8 av1 = *(const s16x8*)(vbs + (32 + l31) * 64 + offv);           \
        O0 = __builtin_amdgcn_mfma_f32_32x32x16_bf16(av0, pb_.v, O0, 0, 0, 0); \
        O1 = __builtin_amdgcn_mfma_f32_32x32x16_bf16(av1, pb_.v, O1, 0, 0, 0); \
        lAcc = __builtin_amdgcn_mfma_f32_32x32x16_bf16(ones, pb_.v, lAcc, 0, 0, 0); \
    } while (0)
        PVBLK(S0, 0, 0);
        PVBLK(S0, 8, 1);
        PVBLK(S1, 0, 2);
        PVBLK(S1, 8, 3);
#undef PVBLK
        __builtin_amdgcn_s_setprio(0);
    }

    // l for q = qbase + l31: every reg/half-lane of lAcc holds the full sum
    if (lh == 0) lArr[w * 32 + l31] = lAcc[0];

    __syncthreads();    // drain last PV's LDS reads before Lo overwrites sm

    // stash raw O^T (fp32) per wave: Lo[w][q 0..31][d 0..67(pad)]
    float* Lo = (float*)sm + w * 2176;
#pragma unroll
    for (int dt = 0; dt < 2; ++dt) {
        const f32x16& Ox = dt ? O1 : O0;
#pragma unroll
        for (int gq = 0; gq < 4; ++gq) {
            int d0 = dt * 32 + gq * 8 + lh * 4;
            float4 vv;
            vv.x = Ox[gq*4+0]; vv.y = Ox[gq*4+1]; vv.z = Ox[gq*4+2]; vv.w = Ox[gq*4+3];
            *(float4*)(Lo + l31 * 68 + d0) = vv;
        }
    }
    __syncthreads();

    // waves 0-3: combine the two kv-half partials, normalize, store
    if (w < 4) {
        const float* LoA = (float*)sm + w * 2176;
        const float* LoB = (float*)sm + (w + 4) * 2176;
#pragma unroll
        for (int it = 0; it < 8; ++it) {
            int ql = it * 4 + (l >> 4);
            float invl = 1.0f / (lArr[w * 32 + ql] + lArr[(w + 4) * 32 + ql]);
            float4 a = *(const float4*)(LoA + ql * 68 + (l & 15) * 4);
            float4 b = *(const float4*)(LoB + ql * 68 + (l & 15) * 4);
            float4 vv;
            vv.x = (a.x + b.x) * invl;
            vv.y = (a.y + b.y) * invl;
            vv.z = (a.z + b.z) * invl;
            vv.w = (a.w + b.w) * invl;
            *(float4*)(out + (qblk * 128 + w * 32 + ql) * 1024 + h * 64 + (l & 15) * 4) = vv;
        }
    }
}

extern "C" void kernel_launch(void* const* d_in, const int* in_sizes, int n_in,
                              void* d_out, int out_size, void* d_ws, size_t ws_size,
                              hipStream_t stream) {
    const float* X     = (const float*)d_in[0];   // [1,4096,1024]
    const float* W     = (const float*)d_in[1];   // [3072,1024]
    const float* bias  = (const float*)d_in[2];   // [3072]
    const float* trace = (const float*)d_in[3];   // [16,64,64]
    float* out = (float*)d_out;

    unsigned short* Qb = (unsigned short*)d_ws;            // 8 MiB [h][s][d] (pre-scaled by CEXP)
    unsigned short* Kb = Qb + 4194304;                     // 8 MiB [h][s][d]
    unsigned short* Vt = Kb + 4194304;                     // 8 MiB [h][d][s] (pre-scaled by trace diag)
    unsigned short* Xb = Vt + 4194304;                     // 8 MiB bf16 X
    unsigned short* Wb = Xb + 4194304;                     // 6 MiB bf16 W

    const size_t NEED_BF16 = (size_t)3 * 8388608 + 8388608 + 6291456;

    if (ws_size >= NEED_BF16) {
        cvt_bf16<<<3584, 256, 0, stream>>>(X, W, Xb, Wb);
        qkv_gemm_bf16<<<dim3(24, 32), 256, 0, stream>>>(Xb, Wb, bias, trace, Qb, Kb, Vt);
    } else {
        qkv_gemm_f32<<<dim3(24, 32), 256, 0, stream>>>(X, W, bias, trace, Qb, Kb, Vt);
    }
    attn<<<512, 512, 0, stream>>>(Qb, Kb, Vt, out);
}

// Round 10
// 194.042 us; speedup vs baseline: 1.1846x; 1.1846x over previous
//
#include <hip/hip_runtime.h>
#include <hip/hip_bf16.h>
#include <stdint.h>

#define S_LEN 4096

typedef short s16x8  __attribute__((ext_vector_type(8)));
typedef float f32x4  __attribute__((ext_vector_type(4)));
typedef float f32x16 __attribute__((ext_vector_type(16)));

// log2(e)/8 : folded into Q at QKV epilogue; attn does exp2(score) directly
#define CEXP 0.18033688011112042f

__device__ __forceinline__ unsigned short f2bf(float f) {
    union { float f; unsigned u; } v; v.f = f;
    unsigned r = v.u + 0x7fffu + ((v.u >> 16) & 1u);
    return (unsigned short)(r >> 16);
}

__device__ __forceinline__ ushort2 pkbf(float a, float b) {
    float2 f; f.x = a; f.y = b;
    __hip_bfloat162 h = __float22bfloat162_rn(f);
    union { __hip_bfloat162 h; ushort2 u; } cv; cv.h = h;
    return cv.u;
}

__device__ __forceinline__ ushort4 pkbf4(float x, float y, float z, float w) {
    ushort2 lo = pkbf(x, y), hi = pkbf(z, w);
    ushort4 r; r.x = lo.x; r.y = lo.y; r.z = hi.x; r.w = hi.y;
    return r;
}

__device__ __forceinline__ unsigned pku(float a, float b) {
    union { ushort2 s; unsigned u; } c; c.s = pkbf(a, b); return c.u;
}

typedef const __attribute__((address_space(1))) void* gas_t;
typedef __attribute__((address_space(3))) void* sas_t;

__device__ __forceinline__ void async16(const void* g, void* s) {
    __builtin_amdgcn_global_load_lds((gas_t)g, (sas_t)s, 16, 0, 0);
}

// ---------------------------------------------------------------------------
// fp32 -> bf16 convert for X (4194304) and W (3145728). 8 elems/thread.
// ---------------------------------------------------------------------------
__global__ __launch_bounds__(256) void cvt_bf16(
    const float* __restrict__ X, const float* __restrict__ W,
    unsigned short* __restrict__ Xb, unsigned short* __restrict__ Wb)
{
    const long NX = 4194304;
    long i = (long)(blockIdx.x * 256 + threadIdx.x) * 8;
    const float* src; unsigned short* dst; long off;
    if (i < NX) { src = X; dst = Xb; off = i; }
    else        { src = W; dst = Wb; off = i - NX; }
    float4 a = *(const float4*)(src + off);
    float4 b = *(const float4*)(src + off + 4);
    union { s16x8 v; ushort4 q[2]; } o;
    o.q[0] = pkbf4(a.x, a.y, a.z, a.w);
    o.q[1] = pkbf4(b.x, b.y, b.z, b.w);
    *(s16x8*)(dst + off) = o.v;
}

// ---------------------------------------------------------------------------
// Kernel A (primary): qkv = Xb @ Wb^T + b, bf16 in. (R7 version — session best)
// BK=32 dbuf (2x16KB staging, 34816B LDS block) -> 4 blocks/CU, all 768
// blocks resident, 1 barrier/kt. Vectorized Q/K epilogue.
// ---------------------------------------------------------------------------
__global__ __launch_bounds__(256) void qkv_gemm_bf16(
    const unsigned short* __restrict__ Xb, const unsigned short* __restrict__ Wb,
    const float* __restrict__ bias, const float* __restrict__ trace,
    unsigned short* __restrict__ Qb, unsigned short* __restrict__ Kb,
    unsigned short* __restrict__ Vt)
{
    __shared__ __align__(16) unsigned short sm[17408];   // 34816 B

    const int t = threadIdx.x;
    const int l = t & 63;
    const int w = t >> 6;
    const int bm = blockIdx.y, bn = blockIdx.x;
    const int rowBase = (w >> 1) * 64;
    const int colBase = (w & 1) * 64;

    f32x4 acc[4][4];
#pragma unroll
    for (int i = 0; i < 4; i++)
#pragma unroll
        for (int j = 0; j < 4; j++) acc[i][j] = (f32x4)0.f;

    const int p0 = w * 128 + l;
    const int p1 = p0 + 64;
    const int ar0 = p0 >> 2, ac0 = (p0 & 3) * 8;
    const int ar1 = p1 >> 2, ac1 = (p1 & 3) * 8;

    async16(Xb + (bm * 128 + ar0) * 1024 + ac0, sm + p0 * 8);
    async16(Xb + (bm * 128 + ar1) * 1024 + ac1, sm + p1 * 8);
    async16(Wb + (bn * 128 + ar0) * 1024 + ac0, sm + 4096 + p0 * 8);
    async16(Wb + (bn * 128 + ar1) * 1024 + ac1, sm + 4096 + p1 * 8);

    for (int kt = 0; kt < 32; ++kt) {
        __syncthreads();
        const unsigned short* As = sm + (kt & 1) * 8192;
        const unsigned short* Bs = As + 4096;

        if (kt < 31) {
            const int k0 = (kt + 1) * 32;
            unsigned short* An = sm + ((kt + 1) & 1) * 8192;
            async16(Xb + (bm * 128 + ar0) * 1024 + k0 + ac0, An + p0 * 8);
            async16(Xb + (bm * 128 + ar1) * 1024 + k0 + ac1, An + p1 * 8);
            async16(Wb + (bn * 128 + ar0) * 1024 + k0 + ac0, An + 4096 + p0 * 8);
            async16(Wb + (bn * 128 + ar1) * 1024 + k0 + ac1, An + 4096 + p1 * 8);
        }

        s16x8 af[4], bf[4];
#pragma unroll
        for (int i = 0; i < 4; i++) {
            af[i] = *(const s16x8*)(As + (rowBase + i * 16 + (l & 15)) * 32 + (l >> 4) * 8);
            bf[i] = *(const s16x8*)(Bs + (colBase + i * 16 + (l & 15)) * 32 + (l >> 4) * 8);
        }
#pragma unroll
        for (int i = 0; i < 4; i++)
#pragma unroll
            for (int j = 0; j < 4; j++)
                acc[i][j] = __builtin_amdgcn_mfma_f32_16x16x32_bf16(af[i], bf[j], acc[i][j], 0, 0, 0);
    }

    __syncthreads();

    if (bn < 16) {
        unsigned short* Ls = sm;                  // [128 s][136 c]
        const int region = bn >> 3;
        unsigned short* dst = region ? Kb : Qb;
        const float scl = region ? 1.0f : CEXP;
#pragma unroll
        for (int j = 0; j < 4; j++) {
            int cl = colBase + j * 16 + (l & 15);
            float bv = bias[bn * 128 + cl];
#pragma unroll
            for (int i = 0; i < 4; i++) {
                int s0 = rowBase + i * 16 + ((l >> 4) << 2);
#pragma unroll
                for (int r = 0; r < 4; r++)
                    Ls[(s0 + r) * 136 + cl] = f2bf((acc[i][j][r] + bv) * scl);
            }
        }
        __syncthreads();
#pragma unroll
        for (int p = 0; p < 8; ++p) {
            int tk = p * 256 + t;
            int s  = tk >> 4;
            int ch = tk & 15;
            int gc = bn * 128 + ch * 8;
            int h  = (gc >> 6) & 15, d = gc & 63;
            s16x8 v = *(const s16x8*)(Ls + s * 136 + ch * 8);
            *(s16x8*)(dst + (h * S_LEN + bm * 128 + s) * 64 + d) = v;
        }
    } else {
        unsigned short* Lt = sm;              // 128 x 136
#pragma unroll
        for (int j = 0; j < 4; j++) {
            int cl = colBase + j * 16 + (l & 15);
            int o  = bn * 128 + cl - 2048;
            float bv = bias[bn * 128 + cl];
            float tr = trace[(o >> 6) * 4096 + (o & 63) * 65];
#pragma unroll
            for (int i = 0; i < 4; i++) {
                int s0 = rowBase + i * 16 + ((l >> 4) << 2);
                *(ushort4*)(Lt + cl * 136 + s0) =
                    pkbf4((acc[i][j][0] + bv) * tr, (acc[i][j][1] + bv) * tr,
                          (acc[i][j][2] + bv) * tr, (acc[i][j][3] + bv) * tr);
            }
        }
        __syncthreads();
#pragma unroll
        for (int p = 0; p < 8; ++p) {
            int dl  = (t >> 4) + p * 16;
            int sch = (t & 15) * 8;
            int o = bn * 128 + dl - 2048;
            int h = o >> 6, d = o & 63;
            s16x8 v = *(const s16x8*)(Lt + dl * 136 + sch);
            *(s16x8*)(Vt + (h * 64 + d) * S_LEN + bm * 128 + sch) = v;
        }
    }
}

// ---------------------------------------------------------------------------
// Kernel A (fallback, small ws): fp32-staged GEMM, same outputs (unchanged)
// ---------------------------------------------------------------------------
__global__ __launch_bounds__(256) void qkv_gemm_f32(
    const float* __restrict__ X, const float* __restrict__ W,
    const float* __restrict__ bias, const float* __restrict__ trace,
    unsigned short* __restrict__ Qb, unsigned short* __restrict__ Kb,
    unsigned short* __restrict__ Vt)
{
    __shared__ __align__(16) unsigned short sm[17408];
    unsigned short* As = sm;
    unsigned short* Bs = sm + 5120;

    const int t = threadIdx.x;
    const int l = t & 63;
    const int w = t >> 6;
    const int bm = blockIdx.y, bn = blockIdx.x;
    const int rowBase = (w >> 1) * 64;
    const int colBase = (w & 1) * 64;

    f32x4 acc[4][4];
#pragma unroll
    for (int i = 0; i < 4; i++)
#pragma unroll
        for (int j = 0; j < 4; j++) acc[i][j] = (f32x4)0.f;

    const int sr = t >> 3;
    const int sc = (t & 7) * 4;

    for (int kt = 0; kt < 32; ++kt) {
        const int k0 = kt * 32;
#pragma unroll
        for (int p = 0; p < 4; ++p) {
            int r = sr + p * 32;
            float4 xa = *(const float4*)(X + (bm * 128 + r) * 1024 + k0 + sc);
            float4 wb = *(const float4*)(W + (bn * 128 + r) * 1024 + k0 + sc);
            *(ushort4*)(As + r * 40 + sc) = pkbf4(xa.x, xa.y, xa.z, xa.w);
            *(ushort4*)(Bs + r * 40 + sc) = pkbf4(wb.x, wb.y, wb.z, wb.w);
        }
        __syncthreads();

        s16x8 af[4], bf[4];
#pragma unroll
        for (int i = 0; i < 4; i++) {
            af[i] = *(const s16x8*)(As + (rowBase + i * 16 + (l & 15)) * 40 + (l >> 4) * 8);
            bf[i] = *(const s16x8*)(Bs + (colBase + i * 16 + (l & 15)) * 40 + (l >> 4) * 8);
        }
#pragma unroll
        for (int i = 0; i < 4; i++)
#pragma unroll
            for (int j = 0; j < 4; j++)
                acc[i][j] = __builtin_amdgcn_mfma_f32_16x16x32_bf16(af[i], bf[j], acc[i][j], 0, 0, 0);
        __syncthreads();
    }

    if (bn < 16) {
#pragma unroll
        for (int j = 0; j < 4; j++) {
            int col = bn * 128 + colBase + j * 16 + (l & 15);
            float bv = bias[col];
            int region = col >> 10;
            int within = col & 1023;
            int h = within >> 6, d = within & 63;
            unsigned short* dst = (region == 0) ? Qb : Kb;
            float scl = (region == 0) ? CEXP : 1.0f;
#pragma unroll
            for (int i = 0; i < 4; i++) {
                int s0 = bm * 128 + rowBase + i * 16 + ((l >> 4) << 2);
#pragma unroll
                for (int r = 0; r < 4; r++)
                    dst[(h * S_LEN + s0 + r) * 64 + d] = f2bf((acc[i][j][r] + bv) * scl);
            }
        }
    } else {
        __syncthreads();
        unsigned short* Lt = sm;
#pragma unroll
        for (int j = 0; j < 4; j++) {
            int cl = colBase + j * 16 + (l & 15);
            int o  = bn * 128 + cl - 2048;
            float bv = bias[bn * 128 + cl];
            float tr = trace[(o >> 6) * 4096 + (o & 63) * 65];
#pragma unroll
            for (int i = 0; i < 4; i++) {
                int s0 = rowBase + i * 16 + ((l >> 4) << 2);
                *(ushort4*)(Lt + cl * 136 + s0) =
                    pkbf4((acc[i][j][0] + bv) * tr, (acc[i][j][1] + bv) * tr,
                          (acc[i][j][2] + bv) * tr, (acc[i][j][3] + bv) * tr);
            }
        }
        __syncthreads();
#pragma unroll
        for (int p = 0; p < 8; ++p) {
            int dl  = (t >> 4) + p * 16;
            int sch = (t & 15) * 8;
            int o = bn * 128 + dl - 2048;
            int h = o >> 6, d = o & 63;
            s16x8 v = *(const s16x8*)(Lt + dl * 136 + sch);
            *(s16x8*)(Vt + (h * 64 + d) * S_LEN + bm * 128 + sch) = v;
        }
    }
}

// ---------------------------------------------------------------------------
// Kernel B: flash attention (exact R7 version — session-best 88.8 µs).
// DMA dbuf staging (zero staging regs), 1 barrier/kt, T12 in-register P,
// T5 setprio, XOR-swizzled [64][64] K/V layout. Bank conflicts (8.5M) are
// PROVEN latency-hidden (R8: removing them cost +2 µs in staging overhead);
// VALU l-sum stays on VALU (R9: matrix-pipe l-sum exceeds the 64-VGPR pin
// -> 33MB/dispatch scratch spill, +38 µs). 64 VGPRs is the hard budget.
// ---------------------------------------------------------------------------
__global__ __launch_bounds__(512, 4) void attn(
    const unsigned short* __restrict__ Qb, const unsigned short* __restrict__ Kb,
    const unsigned short* __restrict__ Vt, float* __restrict__ out)
{
    __shared__ __align__(16) unsigned short sm[34816];   // 69632 B
    __shared__ float lArr[256];

    const int t = threadIdx.x;
    const int l = t & 63;
    const int w = t >> 6;            // 0..7
    const int g = w >> 2;            // kv half
    const int wg = w & 3;            // wave within group
    const int wq = w & 3;            // q sub-tile
    // XCD swizzle: xcd = bid%8 owns heads {2*xcd, 2*xcd+1}
    const int bid = blockIdx.x;
    const int xcd = bid & 7;
    const int j   = bid >> 3;        // 0..63
    const int h   = xcd * 2 + (j & 1);
    const int qblk = j >> 1;         // 0..31
    const int qbase = qblk * 128 + wq * 32;
    const int l31 = l & 31;
    const int lh  = l >> 5;
    const int swz = l31 & 7;         // read-side XOR (row&7)

    s16x8 qf[4];
#pragma unroll
    for (int ks = 0; ks < 4; ks++)
        qf[ks] = *(const s16x8*)(Qb + (h * S_LEN + qbase + l31) * 64 + ks * 16 + lh * 8);

    f32x16 O0 = (f32x16)0.f, O1 = (f32x16)0.f;
    float2 lpA; lpA.x = 0.f; lpA.y = 0.f;
    float2 lpB; lpB.x = 0.f; lpB.y = 0.f;

    // --- DMA staging addresses -------------------------------------------
    const int p0 = (wg * 2 + 0) * 64 + l;
    const int p1 = (wg * 2 + 1) * 64 + l;
    const int r0_ = p0 >> 3, c0_ = (p0 & 7) ^ (r0_ & 7);
    const int r1_ = p1 >> 3, c1_ = (p1 & 7) ^ (r1_ & 7);
    const unsigned short* gk0 = Kb + (h * S_LEN + g * 2048 + r0_) * 64 + c0_ * 8;
    const unsigned short* gk1 = Kb + (h * S_LEN + g * 2048 + r1_) * 64 + c1_ * 8;
    const unsigned short* gv0 = Vt + (h * 64 + r0_) * S_LEN + g * 2048 + c0_ * 8;
    const unsigned short* gv1 = Vt + (h * 64 + r1_) * S_LEN + g * 2048 + c1_ * 8;

    // prologue: stage tile 0 into buf 0
    {
        unsigned short* kb_ = sm + g * 8192 + wg * 1024;
        async16(gk0, kb_);
        async16(gk1, kb_ + 512);
        async16(gv0, kb_ + 4096);
        async16(gv1, kb_ + 4096 + 512);
    }

    for (int kt = 0; kt < 32; ++kt) {
        __syncthreads();   // implicit vmcnt(0): buf[kt&1] DMA done everywhere;
                           // all waves finished reading buf[kt&1 ^ 1]
        const unsigned short* sb  = sm + ((kt & 1) * 2 + g) * 8192;
        const unsigned short* vbs = sb + 4096;

        // issue next tile's DMA into the other buffer (zero registers)
        if (kt < 31) {
            gk0 += 4096; gk1 += 4096; gv0 += 64; gv1 += 64;
            unsigned short* kb_ = sm + (((kt + 1) & 1) * 2 + g) * 8192 + wg * 1024;
            async16(gk0, kb_);
            async16(gk1, kb_ + 512);
            async16(gv0, kb_ + 4096);
            async16(gv1, kb_ + 4096 + 512);
        }

        // S^T[kv][q] = K x Q^T  (scores pre-scaled via Q); swizzled reads
        f32x16 S0 = (f32x16)0.f, S1 = (f32x16)0.f;
        __builtin_amdgcn_s_setprio(1);
#pragma unroll
        for (int ks = 0; ks < 4; ks++) {
            const int off = ((ks * 2 + lh) ^ swz) * 8;
            s16x8 a0 = *(const s16x8*)(sb + l31 * 64 + off);
            s16x8 a1 = *(const s16x8*)(sb + (32 + l31) * 64 + off);
            S0 = __builtin_amdgcn_mfma_f32_32x32x16_bf16(a0, qf[ks], S0, 0, 0, 0);
            S1 = __builtin_amdgcn_mfma_f32_32x32x16_bf16(a1, qf[ks], S1, 0, 0, 0);
        }
        __builtin_amdgcn_s_setprio(0);

#pragma unroll
        for (int i = 0; i < 16; i += 4) {
            float p0v = __builtin_amdgcn_exp2f(S0[i+0]); S0[i+0] = p0v; lpA.x += p0v;
            float p1v = __builtin_amdgcn_exp2f(S0[i+1]); S0[i+1] = p1v; lpA.y += p1v;
            float p2v = __builtin_amdgcn_exp2f(S0[i+2]); S0[i+2] = p2v; lpB.x += p2v;
            float p3v = __builtin_amdgcn_exp2f(S0[i+3]); S0[i+3] = p3v; lpB.y += p3v;
        }
#pragma unroll
        for (int i = 0; i < 16; i += 4) {
            float p0v = __builtin_amdgcn_exp2f(S1[i+0]); S1[i+0] = p0v; lpA.x += p0v;
            float p1v = __builtin_amdgcn_exp2f(S1[i+1]); S1[i+1] = p1v; lpA.y += p1v;
            float p2v = __builtin_amdgcn_exp2f(S1[i+2]); S1[i+2] = p2v; lpB.x += p2v;
            float p3v = __builtin_amdgcn_exp2f(S1[i+3]); S1[i+3] = p3v; lpB.y += p3v;
        }

        // T12: O^T[d][q] += V^T x P^T, P built in-register (R1-verified map).
        __builtin_amdgcn_s_setprio(1);
#define PVBLK(SX, BO, KS) do {                                               \
        unsigned pa0 = pku(SX[(BO)+0], SX[(BO)+1]);                          \
        unsigned pc0 = pku(SX[(BO)+4], SX[(BO)+5]);                          \
        unsigned pa1 = pku(SX[(BO)+2], SX[(BO)+3]);                          \
        unsigned pc1 = pku(SX[(BO)+6], SX[(BO)+7]);                          \
        auto r0 = __builtin_amdgcn_permlane32_swap(pa0, pc0, false, false);  \
        auto r1 = __builtin_amdgcn_permlane32_swap(pa1, pc1, false, false);  \
        union { s16x8 v; unsigned u[4]; } pb_;                               \
        pb_.u[0] = r0[0]; pb_.u[1] = r1[0]; pb_.u[2] = r0[1]; pb_.u[3] = r1[1]; \
        const int offv = (((KS) * 2 + lh) ^ swz) * 8;                        \
        s16x8 av0 = *(const s16x8*)(vbs + l31 * 64 + offv);                  \
        s16x8 av1 = *(const s16x8*)(vbs + (32 + l31) * 64 + offv);           \
        O0 = __builtin_amdgcn_mfma_f32_32x32x16_bf16(av0, pb_.v, O0, 0, 0, 0); \
        O1 = __builtin_amdgcn_mfma_f32_32x32x16_bf16(av1, pb_.v, O1, 0, 0, 0); \
    } while (0)
        PVBLK(S0, 0, 0);
        PVBLK(S0, 8, 1);
        PVBLK(S1, 0, 2);
        PVBLK(S1, 8, 3);
#undef PVBLK
        __builtin_amdgcn_s_setprio(0);
    }

    // per-wave l partial for q = qbase + l31
    float l_part = (lpA.x + lpA.y) + (lpB.x + lpB.y);
    float l_tot = l_part + __shfl_xor(l_part, 32);
    if (lh == 0) lArr[w * 32 + l31] = l_tot;

    __syncthreads();    // drain last PV's LDS reads before Lo overwrites sm

    // stash raw O^T (fp32) per wave: Lo[w][q 0..31][d 0..67(pad)]
    float* Lo = (float*)sm + w * 2176;
#pragma unroll
    for (int dt = 0; dt < 2; ++dt) {
        const f32x16& Ox = dt ? O1 : O0;
#pragma unroll
        for (int gq = 0; gq < 4; ++gq) {
            int d0 = dt * 32 + gq * 8 + lh * 4;
            float4 vv;
            vv.x = Ox[gq*4+0]; vv.y = Ox[gq*4+1]; vv.z = Ox[gq*4+2]; vv.w = Ox[gq*4+3];
            *(float4*)(Lo + l31 * 68 + d0) = vv;
        }
    }
    __syncthreads();

    // waves 0-3: combine the two kv-half partials, normalize, store
    if (w < 4) {
        const float* LoA = (float*)sm + w * 2176;
        const float* LoB = (float*)sm + (w + 4) * 2176;
#pragma unroll
        for (int it = 0; it < 8; ++it) {
            int ql = it * 4 + (l >> 4);
            float invl = 1.0f / (lArr[w * 32 + ql] + lArr[(w + 4) * 32 + ql]);
            float4 a = *(const float4*)(LoA + ql * 68 + (l & 15) * 4);
            float4 b = *(const float4*)(LoB + ql * 68 + (l & 15) * 4);
            float4 vv;
            vv.x = (a.x + b.x) * invl;
            vv.y = (a.y + b.y) * invl;
            vv.z = (a.z + b.z) * invl;
            vv.w = (a.w + b.w) * invl;
            *(float4*)(out + (qblk * 128 + w * 32 + ql) * 1024 + h * 64 + (l & 15) * 4) = vv;
        }
    }
}

extern "C" void kernel_launch(void* const* d_in, const int* in_sizes, int n_in,
                              void* d_out, int out_size, void* d_ws, size_t ws_size,
                              hipStream_t stream) {
    const float* X     = (const float*)d_in[0];   // [1,4096,1024]
    const float* W     = (const float*)d_in[1];   // [3072,1024]
    const float* bias  = (const float*)d_in[2];   // [3072]
    const float* trace = (const float*)d_in[3];   // [16,64,64]
    float* out = (float*)d_out;

    unsigned short* Qb = (unsigned short*)d_ws;            // 8 MiB [h][s][d] (pre-scaled by CEXP)
    unsigned short* Kb = Qb + 4194304;                     // 8 MiB [h][s][d]
    unsigned short* Vt = Kb + 4194304;                     // 8 MiB [h][d][s] (pre-scaled by trace diag)
    unsigned short* Xb = Vt + 4194304;                     // 8 MiB bf16 X
    unsigned short* Wb = Xb + 4194304;                     // 6 MiB bf16 W

    const size_t NEED_BF16 = (size_t)3 * 8388608 + 8388608 + 6291456;

    if (ws_size >= NEED_BF16) {
        cvt_bf16<<<3584, 256, 0, stream>>>(X, W, Xb, Wb);
        qkv_gemm_bf16<<<dim3(24, 32), 256, 0, stream>>>(Xb, Wb, bias, trace, Qb, Kb, Vt);
    } else {
        qkv_gemm_f32<<<dim3(24, 32), 256, 0, stream>>>(X, W, bias, trace, Qb, Kb, Vt);
    }
    attn<<<512, 512, 0, stream>>>(Qb, Kb, Vt, out);
}